// Round 1
// baseline (873.613 us; speedup 1.0000x reference)
//
#include <hip/hip_runtime.h>
#include <math.h>

#define NN 2048      // nodes
#define D  128       // feature dim
#define EE 65536     // edges
#define EPSF 1e-6f

// ---------------- init: zero out + a_sum, amax = -inf ----------------
__global__ void k0_init(float* __restrict__ o, float* __restrict__ a_sum,
                        unsigned int* __restrict__ amax_bits) {
    int i = blockIdx.x * blockDim.x + threadIdx.x;
    if (i < NN * D) o[i] = 0.f;
    if (i < NN) a_sum[i] = 0.f;
    if (i == 0) *amax_bits = 0xFF800000u;  // -inf
}

// ---------------- per-node projections: U = x@fW[:128], V = x@fW[128:],
//                  p = x@wW[:128], q = x@wW[128:] ----------------
__global__ __launch_bounds__(128) void k1_node_proj(
        const float* __restrict__ x, const float* __restrict__ fW,
        const float* __restrict__ wW,
        float* __restrict__ U, float* __restrict__ V,
        float* __restrict__ p, float* __restrict__ q) {
    int n = blockIdx.x;
    int t = threadIdx.x;
    __shared__ float xs[D];
    xs[t] = x[n * D + t];
    __syncthreads();
    float u = 0.f, v = 0.f;
#pragma unroll 8
    for (int k = 0; k < D; ++k) {
        float xv = xs[k];
        u = fmaf(xv, fW[k * D + t], u);
        v = fmaf(xv, fW[(k + D) * D + t], v);
    }
    U[n * D + t] = u;
    V[n * D + t] = v;

    float pp = xs[t] * wW[t];
    float qq = xs[t] * wW[D + t];
#pragma unroll
    for (int off = 32; off > 0; off >>= 1) {
        pp += __shfl_down(pp, off, 64);
        qq += __shfl_down(qq, off, 64);
    }
    __shared__ float red[4];
    int wave = t >> 6;
    if ((t & 63) == 0) { red[wave * 2] = pp; red[wave * 2 + 1] = qq; }
    __syncthreads();
    if (t == 0) {
        p[n] = red[0] + red[2];
        q[n] = red[1] + red[3];
    }
}

// ---------------- per-edge logits + global max ----------------
__global__ __launch_bounds__(256) void k2a_logit_max(
        const int* __restrict__ src, const int* __restrict__ tgt,
        const float* __restrict__ p, const float* __restrict__ q,
        const float* __restrict__ wb,
        float* __restrict__ a, unsigned int* __restrict__ amax_bits) {
    int i = blockIdx.x * blockDim.x + threadIdx.x;
    float local = -INFINITY;
    float wbv = wb[0];
    for (int e = i; e < EE; e += gridDim.x * blockDim.x) {
        float ae = p[src[e]] + q[tgt[e]] + wbv;
        a[e] = ae;
        local = fmaxf(local, ae);
    }
#pragma unroll
    for (int off = 32; off > 0; off >>= 1)
        local = fmaxf(local, __shfl_down(local, off, 64));
    __shared__ float smax[4];
    if ((threadIdx.x & 63) == 0) smax[threadIdx.x >> 6] = local;
    __syncthreads();
    if (threadIdx.x == 0) {
        float m = fmaxf(fmaxf(smax[0], smax[1]), fmaxf(smax[2], smax[3]));
        // float atomic max via int/uint ordering trick (amax init'd to -inf)
        if (m >= 0.f) atomicMax((int*)amax_bits, __float_as_int(m));
        else          atomicMin(amax_bits, __float_as_uint(m));
    }
}

// ---------------- exp + per-target denominator (in-place a -> aexp) ----------------
__global__ __launch_bounds__(256) void k2b_exp_sum(
        const int* __restrict__ tgt, float* __restrict__ a,
        const unsigned int* __restrict__ amax_bits,
        float* __restrict__ a_sum) {
    float amax = __uint_as_float(*amax_bits);
    int i = blockIdx.x * blockDim.x + threadIdx.x;
    for (int e = i; e < EE; e += gridDim.x * blockDim.x) {
        float ae = expf(a[e] - amax);
        a[e] = ae;  // now holds aexp
        atomicAdd(&a_sum[tgt[e]], ae);
    }
}

// ---------------- per-(edge,component) message + scatter ----------------
__global__ __launch_bounds__(256) void k3_scatter(
        const int* __restrict__ src, const int* __restrict__ tgt,
        const float* __restrict__ U, const float* __restrict__ V,
        const float* __restrict__ fb, const float* __restrict__ aexp,
        float* __restrict__ o) {
    const int total = EE * D;  // 8.4M < 2^31
    for (int idx = blockIdx.x * blockDim.x + threadIdx.x; idx < total;
         idx += gridDim.x * blockDim.x) {
        int e = idx >> 7;
        int c = idx & (D - 1);
        int s = src[e], t = tgt[e];
        float yv = U[s * D + c] + V[t * D + c] + fb[c];
        yv = fmaxf(yv, 0.f) * aexp[e];
        atomicAdd(&o[t * D + c], yv);
    }
}

// ---------------- divide by denominator ----------------
__global__ __launch_bounds__(256) void k4_finalize(
        float* __restrict__ o, const float* __restrict__ a_sum) {
    int i = blockIdx.x * blockDim.x + threadIdx.x;
    if (i < NN * D) o[i] /= (a_sum[i >> 7] + EPSF);
}

extern "C" void kernel_launch(void* const* d_in, const int* in_sizes, int n_in,
                              void* d_out, int out_size, void* d_ws, size_t ws_size,
                              hipStream_t stream) {
    const float* x   = (const float*)d_in[0];
    // d_in[1] = adj (unused)
    const int*   src = (const int*)d_in[2];
    const int*   tgt = (const int*)d_in[3];
    // d_in[4] = Msrc (unused), d_in[5] = Mtgt (unused)
    const float* fW  = (const float*)d_in[6];
    const float* fb  = (const float*)d_in[7];
    const float* wW  = (const float*)d_in[8];
    const float* wb  = (const float*)d_in[9];
    float* o = (float*)d_out;

    float* ws = (float*)d_ws;
    float* U     = ws;                 // NN*D
    float* V     = U + NN * D;         // NN*D
    float* p     = V + NN * D;         // NN
    float* q     = p + NN;             // NN
    float* a     = q + NN;             // EE (logits, then aexp in-place)
    float* a_sum = a + EE;             // NN
    unsigned int* amax_bits = (unsigned int*)(a_sum + NN);  // 1

    k0_init<<<(NN * D + 255) / 256, 256, 0, stream>>>(o, a_sum, amax_bits);
    k1_node_proj<<<NN, 128, 0, stream>>>(x, fW, wW, U, V, p, q);
    k2a_logit_max<<<EE / 256, 256, 0, stream>>>(src, tgt, p, q, wb, a, amax_bits);
    k2b_exp_sum<<<EE / 256, 256, 0, stream>>>(tgt, a, amax_bits, a_sum);
    k3_scatter<<<(EE * D) / 256, 256, 0, stream>>>(src, tgt, U, V, fb, a, o);
    k4_finalize<<<(NN * D + 255) / 256, 256, 0, stream>>>(o, a_sum);
}

// Round 2
// 837.200 us; speedup vs baseline: 1.0435x; 1.0435x over previous
//
#include <hip/hip_runtime.h>
#include <math.h>

#define NN 2048      // nodes
#define D  128       // feature dim
#define EE 65536     // edges
#define EPSF 1e-6f

// ---------------- init: zero degree counts, amax = -inf ----------------
__global__ void k0_init(int* __restrict__ counts, unsigned int* __restrict__ amax_bits) {
    int i = blockIdx.x * blockDim.x + threadIdx.x;
    if (i < NN) counts[i] = 0;
    if (i == 0) *amax_bits = 0xFF800000u;  // -inf
}

// ---------------- per-node projections: U = x@fW[:128], V = x@fW[128:],
//                  p = x@wW[:128], q = x@wW[128:] ----------------
__global__ __launch_bounds__(128) void k1_node_proj(
        const float* __restrict__ x, const float* __restrict__ fW,
        const float* __restrict__ wW,
        float* __restrict__ U, float* __restrict__ V,
        float* __restrict__ p, float* __restrict__ q) {
    int n = blockIdx.x;
    int t = threadIdx.x;
    __shared__ float xs[D];
    xs[t] = x[n * D + t];
    __syncthreads();
    float u = 0.f, v = 0.f;
#pragma unroll 8
    for (int k = 0; k < D; ++k) {
        float xv = xs[k];
        u = fmaf(xv, fW[k * D + t], u);
        v = fmaf(xv, fW[(k + D) * D + t], v);
    }
    U[n * D + t] = u;
    V[n * D + t] = v;

    float pp = xs[t] * wW[t];
    float qq = xs[t] * wW[D + t];
#pragma unroll
    for (int off = 32; off > 0; off >>= 1) {
        pp += __shfl_down(pp, off, 64);
        qq += __shfl_down(qq, off, 64);
    }
    __shared__ float red[4];
    int wave = t >> 6;
    if ((t & 63) == 0) { red[wave * 2] = pp; red[wave * 2 + 1] = qq; }
    __syncthreads();
    if (t == 0) {
        p[n] = red[0] + red[2];
        q[n] = red[1] + red[3];
    }
}

// ---------------- per-edge logits + global max + degree count ----------------
__global__ __launch_bounds__(256) void k2_logit_max_count(
        const int* __restrict__ src, const int* __restrict__ tgt,
        const float* __restrict__ p, const float* __restrict__ q,
        const float* __restrict__ wb,
        float* __restrict__ a, unsigned int* __restrict__ amax_bits,
        int* __restrict__ counts) {
    int i = blockIdx.x * blockDim.x + threadIdx.x;
    float local = -INFINITY;
    float wbv = wb[0];
    for (int e = i; e < EE; e += gridDim.x * blockDim.x) {
        int t = tgt[e];
        float ae = p[src[e]] + q[t] + wbv;
        a[e] = ae;
        local = fmaxf(local, ae);
        atomicAdd(&counts[t], 1);
    }
#pragma unroll
    for (int off = 32; off > 0; off >>= 1)
        local = fmaxf(local, __shfl_down(local, off, 64));
    __shared__ float smax[4];
    if ((threadIdx.x & 63) == 0) smax[threadIdx.x >> 6] = local;
    __syncthreads();
    if (threadIdx.x == 0) {
        float m = fmaxf(fmaxf(smax[0], smax[1]), fmaxf(smax[2], smax[3]));
        if (m >= 0.f) atomicMax((int*)amax_bits, __float_as_int(m));
        else          atomicMin(amax_bits, __float_as_uint(m));
    }
}

// ---------------- exclusive scan of counts -> rowptr, cursor ----------------
__global__ __launch_bounds__(256) void k_scan(const int* __restrict__ counts,
                                              int* __restrict__ rowptr,
                                              int* __restrict__ cursor) {
    __shared__ int sums[256];
    int t = threadIdx.x;
    int base = t * 8;       // 256 threads * 8 = 2048
    int local[8];
    int s = 0;
#pragma unroll
    for (int i = 0; i < 8; ++i) { local[i] = s; s += counts[base + i]; }
    sums[t] = s;
    __syncthreads();
    // Hillis-Steele inclusive scan over 256 partials
    for (int off = 1; off < 256; off <<= 1) {
        int v = sums[t];
        int add = (t >= off) ? sums[t - off] : 0;
        __syncthreads();
        sums[t] = v + add;
        __syncthreads();
    }
    int prefix = (t > 0) ? sums[t - 1] : 0;
#pragma unroll
    for (int i = 0; i < 8; ++i) {
        int rp = prefix + local[i];
        rowptr[base + i] = rp;
        cursor[base + i] = rp;
    }
    if (t == 255) rowptr[NN] = sums[255];
}

// ---------------- fill CSR edge list ----------------
__global__ __launch_bounds__(256) void k_fill(const int* __restrict__ tgt,
                                              int* __restrict__ cursor,
                                              int* __restrict__ elist) {
    int e = blockIdx.x * blockDim.x + threadIdx.x;
    if (e < EE) {
        int pos = atomicAdd(&cursor[tgt[e]], 1);
        elist[pos] = e;
    }
}

// ---------------- per-node gather-aggregate (no atomics) ----------------
__global__ __launch_bounds__(128) void k_agg(
        const int* __restrict__ rowptr, const int* __restrict__ elist,
        const int* __restrict__ src, const float* __restrict__ a,
        const unsigned int* __restrict__ amax_bits,
        const float* __restrict__ U, const float* __restrict__ V,
        const float* __restrict__ fb, float* __restrict__ o) {
    int n = blockIdx.x;
    int c = threadIdx.x;
    float amax = __uint_as_float(*amax_bits);
    float vn = V[n * D + c] + fb[c];
    float acc = 0.f, den = 0.f;
    int jb = rowptr[n], je = rowptr[n + 1];
    for (int j = jb; j < je; ++j) {
        int e = elist[j];
        float aexp = expf(a[e] - amax);   // broadcast scalar per wave
        int s = src[e];
        float yv = fmaxf(U[s * D + c] + vn, 0.f);
        acc = fmaf(yv, aexp, acc);
        den += aexp;
    }
    o[n * D + c] = acc / (den + EPSF);
}

extern "C" void kernel_launch(void* const* d_in, const int* in_sizes, int n_in,
                              void* d_out, int out_size, void* d_ws, size_t ws_size,
                              hipStream_t stream) {
    const float* x   = (const float*)d_in[0];
    // d_in[1] = adj (unused)
    const int*   src = (const int*)d_in[2];
    const int*   tgt = (const int*)d_in[3];
    // d_in[4] = Msrc (unused), d_in[5] = Mtgt (unused)
    const float* fW  = (const float*)d_in[6];
    const float* fb  = (const float*)d_in[7];
    const float* wW  = (const float*)d_in[8];
    const float* wb  = (const float*)d_in[9];
    float* o = (float*)d_out;

    float* ws = (float*)d_ws;
    float* U     = ws;                 // NN*D
    float* V     = U + NN * D;         // NN*D
    float* p     = V + NN * D;         // NN
    float* q     = p + NN;             // NN
    float* a     = q + NN;             // EE (logits)
    unsigned int* amax_bits = (unsigned int*)(a + EE);      // 1 (+pad to 8)
    int* counts = (int*)(amax_bits + 8);                    // NN
    int* rowptr = counts + NN;                              // NN+1 (+pad)
    int* cursor = rowptr + NN + 8;                          // NN
    int* elist  = cursor + NN;                              // EE

    k0_init<<<(NN + 255) / 256, 256, 0, stream>>>(counts, amax_bits);
    k1_node_proj<<<NN, 128, 0, stream>>>(x, fW, wW, U, V, p, q);
    k2_logit_max_count<<<EE / 256, 256, 0, stream>>>(src, tgt, p, q, wb, a,
                                                     amax_bits, counts);
    k_scan<<<1, 256, 0, stream>>>(counts, rowptr, cursor);
    k_fill<<<EE / 256, 256, 0, stream>>>(tgt, cursor, elist);
    k_agg<<<NN, 128, 0, stream>>>(rowptr, elist, src, a, amax_bits, U, V, fb, o);
}

// Round 3
// 822.963 us; speedup vs baseline: 1.0615x; 1.0173x over previous
//
#include <hip/hip_runtime.h>
#include <math.h>

#define NN 2048      // nodes
#define D  128       // feature dim
#define EE 65536     // edges (== NN*32)
#define EPB 32       // edges per k1 block (EE/NN)
#define CAP 512      // LDS edge cache per node (max degree ~60 in practice)
#define EPSF 1e-6f

// ---------------- per-node projections + fused degree count ----------------
// U = x@fW[:128], V = x@fW[128:], p = x@wW[:128], q = x@wW[128:]
// block n additionally counts edges [n*32, n*32+32) into counts[] (atomics).
__global__ __launch_bounds__(128) void k1_proj_count(
        const float* __restrict__ x, const float* __restrict__ fW,
        const float* __restrict__ wW, const int* __restrict__ tgt,
        float* __restrict__ U, float* __restrict__ V,
        float* __restrict__ p, float* __restrict__ q,
        int* __restrict__ counts) {
    int n = blockIdx.x;
    int t = threadIdx.x;

    if (t < EPB) atomicAdd(&counts[tgt[n * EPB + t]], 1);

    __shared__ float xs[D];
    xs[t] = x[n * D + t];
    __syncthreads();
    float u = 0.f, v = 0.f;
#pragma unroll 8
    for (int k = 0; k < D; ++k) {
        float xv = xs[k];
        u = fmaf(xv, fW[k * D + t], u);
        v = fmaf(xv, fW[(k + D) * D + t], v);
    }
    U[n * D + t] = u;
    V[n * D + t] = v;

    float pp = xs[t] * wW[t];
    float qq = xs[t] * wW[D + t];
#pragma unroll
    for (int off = 32; off > 0; off >>= 1) {
        pp += __shfl_down(pp, off, 64);
        qq += __shfl_down(qq, off, 64);
    }
    __shared__ float red[4];
    int wave = t >> 6;
    if ((t & 63) == 0) { red[wave * 2] = pp; red[wave * 2 + 1] = qq; }
    __syncthreads();
    if (t == 0) {
        p[n] = red[0] + red[2];
        q[n] = red[1] + red[3];
    }
}

// ---------------- exclusive scan of counts -> rowptr, cursor ----------------
__global__ __launch_bounds__(256) void k_scan(const int* __restrict__ counts,
                                              int* __restrict__ rowptr,
                                              int* __restrict__ cursor) {
    __shared__ int sums[256];
    int t = threadIdx.x;
    int base = t * 8;       // 256 threads * 8 = 2048
    int local[8];
    int s = 0;
#pragma unroll
    for (int i = 0; i < 8; ++i) { local[i] = s; s += counts[base + i]; }
    sums[t] = s;
    __syncthreads();
    for (int off = 1; off < 256; off <<= 1) {
        int v = sums[t];
        int add = (t >= off) ? sums[t - off] : 0;
        __syncthreads();
        sums[t] = v + add;
        __syncthreads();
    }
    int prefix = (t > 0) ? sums[t - 1] : 0;
#pragma unroll
    for (int i = 0; i < 8; ++i) {
        int rp = prefix + local[i];
        rowptr[base + i] = rp;
        cursor[base + i] = rp;
    }
    if (t == 255) rowptr[NN] = sums[255];
}

// ---------------- fill CSR edge list ----------------
__global__ __launch_bounds__(256) void k_fill(const int* __restrict__ tgt,
                                              int* __restrict__ cursor,
                                              int* __restrict__ elist) {
    int e = blockIdx.x * blockDim.x + threadIdx.x;
    if (e < EE) {
        int pos = atomicAdd(&cursor[tgt[e]], 1);
        elist[pos] = e;
    }
}

// ---------------- per-node aggregate: logits, per-node softmax, gather ----
// Per-node max shift m_n instead of the reference's global max: result
// differs only via EPS * exp(m_n - amax_global) <= EPS (rel ~1e-7) — far
// below the 7.7e-2 threshold.
__global__ __launch_bounds__(128) void k_agg(
        const int* __restrict__ rowptr, const int* __restrict__ elist,
        const int* __restrict__ src,
        const float* __restrict__ p, const float* __restrict__ q,
        const float* __restrict__ wb,
        const float* __restrict__ U, const float* __restrict__ V,
        const float* __restrict__ fb, float* __restrict__ o) {
    int n = blockIdx.x;
    int t = threadIdx.x;
    int jb = rowptr[n], je = rowptr[n + 1];
    int deg = je - jb;

    __shared__ int   s_src[CAP];
    __shared__ float s_axp[CAP];
    __shared__ float warpm[2], warpd[2];

    float qn = q[n] + wb[0];

    // pass 1: logits -> LDS cache, per-node max
    float lm = -INFINITY;
    for (int j = t; j < deg; j += 128) {
        int e = elist[jb + j];
        int s = src[e];
        float ae = p[s] + qn;
        if (j < CAP) { s_src[j] = s; s_axp[j] = ae; }
        lm = fmaxf(lm, ae);
    }
#pragma unroll
    for (int off = 32; off > 0; off >>= 1)
        lm = fmaxf(lm, __shfl_down(lm, off, 64));
    if ((t & 63) == 0) warpm[t >> 6] = lm;
    __syncthreads();
    float m = fmaxf(warpm[0], warpm[1]);

    // pass 2: exp + denominator
    float ld = 0.f;
    for (int j = t; j < deg; j += 128) {
        float ax;
        if (j < CAP) { ax = expf(s_axp[j] - m); s_axp[j] = ax; }
        else { int e = elist[jb + j]; ax = expf(p[src[e]] + qn - m); }
        ld += ax;
    }
#pragma unroll
    for (int off = 32; off > 0; off >>= 1)
        ld += __shfl_down(ld, off, 64);
    if ((t & 63) == 0) warpd[t >> 6] = ld;
    __syncthreads();
    float den = warpd[0] + warpd[1] + EPSF;

    // pass 3: channel-parallel weighted gather
    float vn = V[n * D + t] + fb[t];
    float acc = 0.f;
    int dc = (deg < CAP) ? deg : CAP;
#pragma unroll 4
    for (int j = 0; j < dc; ++j) {
        int s = s_src[j];
        float ax = s_axp[j];
        acc = fmaf(fmaxf(U[s * D + t] + vn, 0.f), ax, acc);
    }
    for (int j = CAP; j < deg; ++j) {   // never taken for this graph size
        int e = elist[jb + j];
        int s = src[e];
        float ax = expf(p[s] + qn - m);
        acc = fmaf(fmaxf(U[s * D + t] + vn, 0.f), ax, acc);
    }
    o[n * D + t] = acc / den;
}

extern "C" void kernel_launch(void* const* d_in, const int* in_sizes, int n_in,
                              void* d_out, int out_size, void* d_ws, size_t ws_size,
                              hipStream_t stream) {
    const float* x   = (const float*)d_in[0];
    // d_in[1] = adj (unused)
    const int*   src = (const int*)d_in[2];
    const int*   tgt = (const int*)d_in[3];
    // d_in[4] = Msrc (unused), d_in[5] = Mtgt (unused)
    const float* fW  = (const float*)d_in[6];
    const float* fb  = (const float*)d_in[7];
    const float* wW  = (const float*)d_in[8];
    const float* wb  = (const float*)d_in[9];
    float* o = (float*)d_out;

    float* ws = (float*)d_ws;
    float* U      = ws;                 // NN*D
    float* V      = U + NN * D;         // NN*D
    float* p      = V + NN * D;         // NN
    float* q      = p + NN;             // NN
    int*   counts = (int*)(q + NN);     // NN
    int*   rowptr = counts + NN;        // NN+1 (+pad)
    int*   cursor = rowptr + NN + 8;    // NN
    int*   elist  = cursor + NN;        // EE

    hipMemsetAsync(counts, 0, NN * sizeof(int), stream);
    k1_proj_count<<<NN, 128, 0, stream>>>(x, fW, wW, tgt, U, V, p, q, counts);
    k_scan<<<1, 256, 0, stream>>>(counts, rowptr, cursor);
    k_fill<<<EE / 256, 256, 0, stream>>>(tgt, cursor, elist);
    k_agg<<<NN, 128, 0, stream>>>(rowptr, elist, src, p, q, wb, U, V, fb, o);
}